// Round 13
// baseline (328.544 us; speedup 1.0000x reference)
//
#include <hip/hip_runtime.h>
#include <hip/hip_fp16.h>
#include <math.h>

#define NN 30000
#define NE 480000
#define NB 118   // ceil(NN/256)
#define SCALE 512.0f
#define INVSCALE (1.0f / 512.0f)

typedef _Float16 half8 __attribute__((ext_vector_type(8)));
typedef float floatx4 __attribute__((ext_vector_type(4)));

__device__ __forceinline__ float lrelu(float v) { return v > 0.0f ? v : v * 0.02f; }

__device__ __forceinline__ float4 fma4(float4 v, float w, float4 a) {
    a.x = fmaf(v.x, w, a.x);
    a.y = fmaf(v.y, w, a.y);
    a.z = fmaf(v.z, w, a.z);
    a.w = fmaf(v.w, w, a.w);
    return a;
}

__device__ __forceinline__ float4 loadh4(const __half* p) {
    uint2 raw = *(const uint2*)p;
    float2 f0 = __half22float2(*(__half2*)&raw.x);
    float2 f1 = __half22float2(*(__half2*)&raw.y);
    return make_float4(f0.x, f0.y, f1.x, f1.y);
}

__device__ __forceinline__ void loadh8(const __half* p, float4* lo, float4* hi) {
    uint4 raw = *(const uint4*)p;
    float2 f0 = __half22float2(*(__half2*)&raw.x);
    float2 f1 = __half22float2(*(__half2*)&raw.y);
    float2 f2 = __half22float2(*(__half2*)&raw.z);
    float2 f3 = __half22float2(*(__half2*)&raw.w);
    *lo = make_float4(f0.x, f0.y, f1.x, f1.y);
    *hi = make_float4(f2.x, f2.y, f3.x, f3.y);
}

// non-temporal csr load: int2 as u64 (little-endian: x = low 32b)
__device__ __forceinline__ int2 ldnt_csr(const int2* p) {
    unsigned long long raw = __builtin_nontemporal_load((const unsigned long long*)p);
    int2 r;
    r.x = (int)(raw & 0xffffffffULL);
    r.y = (int)(raw >> 32);
    return r;
}

// non-temporal half store (value already rounded via __float2half)
__device__ __forceinline__ void stnt_h(__half* p, float v) {
    __half hh = __float2half(v);
    __builtin_nontemporal_store(*(_Float16*)&hh, (_Float16*)p);
}

// ---------------- CSR build (+ fused weight convert + x->fp16) ----------------

__global__ void k_count(const int* __restrict__ ei, int* __restrict__ cnt,
                        const float* __restrict__ W0, const float* __restrict__ Wh,
                        const float* __restrict__ b0, const float* __restrict__ bh,
                        const float* __restrict__ x,
                        __half* __restrict__ W0t, __half* __restrict__ Wht,
                        float* __restrict__ bs, __half* __restrict__ x16) {
    int g = blockIdx.x * 256 + threadIdx.x;
    if (g < NE) atomicAdd(&cnt[ei[NE + g]], 1);
    {   // x -> fp16: 1.92M elements, 4 per thread
        float4 v = *(const float4*)&x[(size_t)g * 4];
        __half2 a = __floats2half2_rn(v.x, v.y);
        __half2 b = __floats2half2_rn(v.z, v.w);
        uint2 pk;
        pk.x = *(unsigned int*)&a;
        pk.y = *(unsigned int*)&b;
        *(uint2*)&x16[(size_t)g * 4] = pk;
    }
    if (g < 8192) {                       // W0 [64,128] -> W0t [128n][64k], *SCALE
        int k = g >> 7, n = g & 127;
        W0t[n * 64 + k] = __float2half(W0[g] * SCALE);
    } else if (g < 8192 + 98304) {        // Wh [6][128,128] -> Wht [6][128n][128k]
        int j = g - 8192;
        int l = j >> 14;
        int r = j & 16383;
        int k = r >> 7, n = r & 127;
        Wht[l * 16384 + n * 128 + k] = __float2half(Wh[j]);
    } else if (g < 8192 + 98304 + 896) {  // biases: [b0 | bh0..bh5] * SCALE
        int j = g - 8192 - 98304;
        bs[j] = (j < 128 ? b0[j] : bh[j - 128]) * SCALE;
    }
}

__global__ void k_scan1(const int* __restrict__ cnt, int* __restrict__ bsum,
                        float* __restrict__ dinv) {
    __shared__ int sd[256];
    int tid = threadIdx.x;
    int i = blockIdx.x * 256 + tid;
    int v = (i < NN) ? cnt[i] : 0;
    if (i < NN) dinv[i] = 1.0f / sqrtf((float)(v + 1));  // +1 self loop
    sd[tid] = v;
    __syncthreads();
    for (int off = 128; off > 0; off >>= 1) {
        if (tid < off) sd[tid] += sd[tid + off];
        __syncthreads();
    }
    if (tid == 0) bsum[blockIdx.x] = sd[0];
}

__global__ void k_scan3(const int* __restrict__ cnt, const int* __restrict__ bsum,
                        int* __restrict__ row_ptr, int* __restrict__ cursor) {
    __shared__ int sd[256];
    __shared__ int offs[128];
    int tid = threadIdx.x;
    if (tid < 128) offs[tid] = (tid < blockIdx.x) ? bsum[tid] : 0;
    __syncthreads();
    for (int o = 64; o > 0; o >>= 1) {
        if (tid < o) offs[tid] += offs[tid + o];
        __syncthreads();
    }
    int i = blockIdx.x * 256 + tid;
    int v = (i < NN) ? cnt[i] : 0;
    sd[tid] = v;
    __syncthreads();
    for (int off = 1; off < 256; off <<= 1) {
        int t = (tid >= off) ? sd[tid - off] : 0;
        __syncthreads();
        sd[tid] += t;
        __syncthreads();
    }
    if (i < NN) {
        int excl = offs[0] + sd[tid] - v;
        row_ptr[i] = excl;
        cursor[i] = excl;
        if (i == NN - 1) row_ptr[NN] = excl + v;
    }
}

__global__ void k_fill(const int* __restrict__ ei, const float* __restrict__ dinv,
                       int* __restrict__ cursor, int2* __restrict__ csr) {
    int e = blockIdx.x * 256 + threadIdx.x;
    if (e < NE) {
        int s = ei[e];
        int d = ei[NE + e];
        int pos = atomicAdd(&cursor[d], 1);
        float w = dinv[s] * dinv[d];
        unsigned long long raw = ((unsigned long long)(unsigned int)__float_as_int(w) << 32) |
                                 (unsigned long long)(unsigned int)s;
        __builtin_nontemporal_store(raw, (unsigned long long*)&csr[pos]);
    }
}

// ================= fused layer kernels: agg -> LDS (A-fragment order) -> MFMA =================
// Block = 16 nodes (one 16-row MFMA tile), 256 threads (4 waves), 16 thr/node agg phase.
// csr reads + h/x16 output stores are NON-TEMPORAL so the gather working set (hin table)
// keeps the per-XCD L2 to itself. Gather loads stay cached.
// // mega-kernel attempt (R11) failed: cooperative launch never ran (all-zero out).

// ---- layer 0: x16 fp16 [NN,64] -> out16 = fp16(lrelu((A_hat x) @ W0t + bias)) ----
__launch_bounds__(256)
__global__ void k_layer0(const __half* __restrict__ x, const int* __restrict__ row_ptr,
                         const int2* __restrict__ csr, const float* __restrict__ dinv,
                         const __half* __restrict__ Wt, const float* __restrict__ bias,
                         __half* __restrict__ out16) {
    __shared__ _Float16 hsF[2 * 4 * 16 * 8];  // 2 KB
    int tid = threadIdx.x;
    int node0 = blockIdx.x * 16;
    {
        int nl = tid >> 4;
        int node = node0 + nl;
        int c = (tid & 15) * 4;          // 4 fp16 ch / lane (8B loads)
        float di = dinv[node];
        float w0 = di * di;
        float4 hv = loadh4(&x[(size_t)node * 64 + c]);
        float4 acc[8];
        acc[0] = make_float4(hv.x * w0, hv.y * w0, hv.z * w0, hv.w * w0);
        #pragma unroll
        for (int j = 1; j < 8; j++) acc[j] = make_float4(0.f, 0.f, 0.f, 0.f);
        int e = row_ptr[node];
        int e1 = row_ptr[node + 1];
        for (; e + 8 <= e1; e += 8) {
            int2 sw[8];
            #pragma unroll
            for (int j = 0; j < 8; j++) sw[j] = ldnt_csr(&csr[e + j]);
            float4 v[8];
            #pragma unroll
            for (int j = 0; j < 8; j++) v[j] = loadh4(&x[(size_t)sw[j].x * 64 + c]);
            #pragma unroll
            for (int j = 0; j < 8; j++) acc[j] = fma4(v[j], __int_as_float(sw[j].y), acc[j]);
        }
        for (; e < e1; ++e) {
            int2 sw = ldnt_csr(&csr[e]);
            float4 v = loadh4(&x[(size_t)sw.x * 64 + c]);
            acc[0] = fma4(v, __int_as_float(sw.y), acc[0]);
        }
        #pragma unroll
        for (int j = 1; j < 8; j++) {
            acc[0].x += acc[j].x;
            acc[0].y += acc[j].y;
            acc[0].z += acc[j].z;
            acc[0].w += acc[j].w;
        }
        int ks = c >> 5, quad = (c >> 3) & 3, jj = c & 7;
        __half2 p0 = __floats2half2_rn(acc[0].x, acc[0].y);
        __half2 p1 = __floats2half2_rn(acc[0].z, acc[0].w);
        uint2 pk;
        pk.x = *(unsigned int*)&p0;
        pk.y = *(unsigned int*)&p1;
        *(uint2*)&hsF[((ks * 4 + quad) * 16 + nl) * 8 + jj] = pk;
    }
    __syncthreads();
    int wave = tid >> 6, lane = tid & 63, quad = lane >> 4, ln = lane & 15;
    half8 afrag[2];
    #pragma unroll
    for (int ks = 0; ks < 2; ks++)
        afrag[ks] = *(const half8*)&hsF[((ks * 4 + quad) * 16 + ln) * 8];
    #pragma unroll
    for (int tc = 0; tc < 2; tc++) {
        int tt = wave + tc * 4;
        floatx4 acc = (floatx4){0.f, 0.f, 0.f, 0.f};
        #pragma unroll
        for (int ks = 0; ks < 2; ks++) {
            half8 b = *(const half8*)&Wt[(size_t)(tt * 16 + ln) * 64 + ks * 32 + quad * 8];
            acc = __builtin_amdgcn_mfma_f32_16x16x32_f16(afrag[ks], b, acc, 0, 0, 0);
        }
        int col = tt * 16 + ln;
        float bb = bias[col];
        #pragma unroll
        for (int r = 0; r < 4; r++) {
            int row = node0 + quad * 4 + r;
            stnt_h(&out16[(size_t)row * 128 + col], lrelu(acc[r] + bb));
        }
    }
}

// ---- hidden layer: h fp16 [NN,128] -> out16 = fp16(lrelu((A_hat h) @ Wt + bias)) ----
// LAST=true: u = h7' @ Wout computed in-block; h7' never hits global.
template <bool LAST>
__launch_bounds__(256)
__global__ void k_layer_h(const __half* __restrict__ h, const int* __restrict__ row_ptr,
                          const int2* __restrict__ csr, const float* __restrict__ dinv,
                          const __half* __restrict__ Wt, const float* __restrict__ bias,
                          __half* __restrict__ out16, const float* __restrict__ Wout,
                          float* __restrict__ u) {
    __shared__ _Float16 hsF[4 * 4 * 16 * 8];  // 4 KB
    __shared__ float uacc[4][16][3];          // cross-wave u partials (LAST only)
    int tid = threadIdx.x;
    int node0 = blockIdx.x * 16;
    {
        int nl = tid >> 4;
        int node = node0 + nl;
        int c = (tid & 15) * 8;      // 8 fp16 ch / lane (16B b128 loads)
        float di = dinv[node];
        float w0 = di * di;
        float4 hlo, hhi;
        loadh8(&h[(size_t)node * 128 + c], &hlo, &hhi);
        float4 acc[4][2];
        acc[0][0] = make_float4(hlo.x * w0, hlo.y * w0, hlo.z * w0, hlo.w * w0);
        acc[0][1] = make_float4(hhi.x * w0, hhi.y * w0, hhi.z * w0, hhi.w * w0);
        #pragma unroll
        for (int j = 1; j < 4; j++) {
            acc[j][0] = make_float4(0.f, 0.f, 0.f, 0.f);
            acc[j][1] = make_float4(0.f, 0.f, 0.f, 0.f);
        }
        int e = row_ptr[node];
        int e1 = row_ptr[node + 1];
        for (; e + 4 <= e1; e += 4) {
            int2 sw[4];
            #pragma unroll
            for (int j = 0; j < 4; j++) sw[j] = ldnt_csr(&csr[e + j]);
            float4 vlo[4], vhi[4];
            #pragma unroll
            for (int j = 0; j < 4; j++)
                loadh8(&h[(size_t)sw[j].x * 128 + c], &vlo[j], &vhi[j]);
            #pragma unroll
            for (int j = 0; j < 4; j++) {
                float w = __int_as_float(sw[j].y);
                acc[j][0] = fma4(vlo[j], w, acc[j][0]);
                acc[j][1] = fma4(vhi[j], w, acc[j][1]);
            }
        }
        for (; e < e1; ++e) {
            int2 sw = ldnt_csr(&csr[e]);
            float4 vlo, vhi;
            loadh8(&h[(size_t)sw.x * 128 + c], &vlo, &vhi);
            float w = __int_as_float(sw.y);
            acc[0][0] = fma4(vlo, w, acc[0][0]);
            acc[0][1] = fma4(vhi, w, acc[0][1]);
        }
        #pragma unroll
        for (int j = 1; j < 4; j++) {
            acc[0][0].x += acc[j][0].x; acc[0][0].y += acc[j][0].y;
            acc[0][0].z += acc[j][0].z; acc[0][0].w += acc[j][0].w;
            acc[0][1].x += acc[j][1].x; acc[0][1].y += acc[j][1].y;
            acc[0][1].z += acc[j][1].z; acc[0][1].w += acc[j][1].w;
        }
        int ks = c >> 5, quad = (c >> 3) & 3;
        __half2 p0 = __floats2half2_rn(acc[0][0].x, acc[0][0].y);
        __half2 p1 = __floats2half2_rn(acc[0][0].z, acc[0][0].w);
        __half2 p2 = __floats2half2_rn(acc[0][1].x, acc[0][1].y);
        __half2 p3 = __floats2half2_rn(acc[0][1].z, acc[0][1].w);
        uint4 pk;
        pk.x = *(unsigned int*)&p0;
        pk.y = *(unsigned int*)&p1;
        pk.z = *(unsigned int*)&p2;
        pk.w = *(unsigned int*)&p3;
        *(uint4*)&hsF[((ks * 4 + quad) * 16 + nl) * 8] = pk;
    }
    __syncthreads();
    int wave = tid >> 6, lane = tid & 63, quad = lane >> 4, ln = lane & 15;
    half8 afrag[4];
    #pragma unroll
    for (int ks = 0; ks < 4; ks++)
        afrag[ks] = *(const half8*)&hsF[((ks * 4 + quad) * 16 + ln) * 8];

    float up[4][3];
    if (LAST) {
        #pragma unroll
        for (int r = 0; r < 4; r++)
            #pragma unroll
            for (int cc = 0; cc < 3; cc++) up[r][cc] = 0.f;
    }

    #pragma unroll
    for (int tc = 0; tc < 2; tc++) {
        int tt = wave + tc * 4;
        floatx4 acc = (floatx4){0.f, 0.f, 0.f, 0.f};
        #pragma unroll
        for (int ks = 0; ks < 4; ks++) {
            half8 b = *(const half8*)&Wt[(size_t)(tt * 16 + ln) * 128 + ks * 32 + quad * 8];
            acc = __builtin_amdgcn_mfma_f32_16x16x32_f16(afrag[ks], b, acc, 0, 0, 0);
        }
        int col = tt * 16 + ln;
        float bb = bias[col];
        if (LAST) {
            float w0o = Wout[col * 3 + 0];
            float w1o = Wout[col * 3 + 1];
            float w2o = Wout[col * 3 + 2];
            #pragma unroll
            for (int r = 0; r < 4; r++) {
                float hv = __half2float(__float2half(lrelu(acc[r] + bb)));
                up[r][0] = fmaf(hv, w0o, up[r][0]);
                up[r][1] = fmaf(hv, w1o, up[r][1]);
                up[r][2] = fmaf(hv, w2o, up[r][2]);
            }
        } else {
            #pragma unroll
            for (int r = 0; r < 4; r++) {
                int row = node0 + quad * 4 + r;
                stnt_h(&out16[(size_t)row * 128 + col], lrelu(acc[r] + bb));
            }
        }
    }

    if (LAST) {
        #pragma unroll
        for (int m = 1; m < 16; m <<= 1) {
            #pragma unroll
            for (int r = 0; r < 4; r++) {
                #pragma unroll
                for (int cc = 0; cc < 3; cc++)
                    up[r][cc] += __shfl_xor(up[r][cc], m);
            }
        }
        if (ln == 0) {
            #pragma unroll
            for (int r = 0; r < 4; r++) {
                #pragma unroll
                for (int cc = 0; cc < 3; cc++)
                    uacc[wave][quad * 4 + r][cc] = up[r][cc];
            }
        }
        __syncthreads();
        if (tid < 48) {
            int row = tid / 3, cc = tid % 3;
            float s = (uacc[0][row][cc] + uacc[1][row][cc]) +
                      (uacc[2][row][cc] + uacc[3][row][cc]);
            u[(size_t)(node0 + row) * 3 + cc] = s;
        }
    }
}

// ---------------- final aggregate (3 ch), unscale, + bias, tanh*0.5 ----------------

__global__ void k_agg_out(const float* __restrict__ u, const int* __restrict__ row_ptr,
                          const int2* __restrict__ csr, const float* __restrict__ dinv,
                          const float* __restrict__ bout, float* __restrict__ out) {
    int node = blockIdx.x * 256 + threadIdx.x;
    if (node >= NN) return;
    float di = dinv[node], w0 = di * di;
    float s0 = u[(size_t)node * 3 + 0] * w0;
    float s1 = u[(size_t)node * 3 + 1] * w0;
    float s2 = u[(size_t)node * 3 + 2] * w0;
    float b0a = 0.f, b1a = 0.f, b2a = 0.f;
    int e = row_ptr[node];
    int e1 = row_ptr[node + 1];
    for (; e + 2 <= e1; e += 2) {
        int2 swa = ldnt_csr(&csr[e]), swb = ldnt_csr(&csr[e + 1]);
        float wa = __int_as_float(swa.y), wb = __int_as_float(swb.y);
        const float* ua = &u[(size_t)swa.x * 3];
        const float* ub = &u[(size_t)swb.x * 3];
        s0 = fmaf(ua[0], wa, s0);
        s1 = fmaf(ua[1], wa, s1);
        s2 = fmaf(ua[2], wa, s2);
        b0a = fmaf(ub[0], wb, b0a);
        b1a = fmaf(ub[1], wb, b1a);
        b2a = fmaf(ub[2], wb, b2a);
    }
    for (; e < e1; ++e) {
        int2 sw = ldnt_csr(&csr[e]);
        float w = __int_as_float(sw.y);
        const float* us = &u[(size_t)sw.x * 3];
        s0 = fmaf(us[0], w, s0);
        s1 = fmaf(us[1], w, s1);
        s2 = fmaf(us[2], w, s2);
    }
    out[(size_t)node * 3 + 0] = tanhf((s0 + b0a) * INVSCALE + bout[0]) * 0.5f;
    out[(size_t)node * 3 + 1] = tanhf((s1 + b1a) * INVSCALE + bout[1]) * 0.5f;
    out[(size_t)node * 3 + 2] = tanhf((s2 + b2a) * INVSCALE + bout[2]) * 0.5f;
}

// ---------------- launch ----------------

extern "C" void kernel_launch(void* const* d_in, const int* in_sizes, int n_in,
                              void* d_out, int out_size, void* d_ws, size_t ws_size,
                              hipStream_t stream) {
    const float* x        = (const float*)d_in[0];
    const int*   ei       = (const int*)d_in[1];   // int32: [2, NE] row-major
    const float* W0       = (const float*)d_in[2];
    const float* b0       = (const float*)d_in[3];
    const float* Wh       = (const float*)d_in[4];
    const float* bh       = (const float*)d_in[5];
    const float* Wout     = (const float*)d_in[6];
    const float* bout     = (const float*)d_in[7];
    float* out            = (float*)d_out;

    char* ws = (char*)d_ws;
    float*  bufA   = (float*)(ws + 0);              // u (NN x 3 fp32) + scan temps
    __half* bufB16 = (__half*)(ws + 15360000);      // NN*128 fp16
    __half* bufC16 = (__half*)(ws + 23040000);      // NN*128 fp16
    __half* x16    = (__half*)(ws + 30720000);      // NN*64 fp16
    __half* W0t16  = (__half*)(ws + 34560000);      // 128*64 fp16
    __half* Wht16  = (__half*)(ws + 34576384);      // 6*128*128 fp16
    float*  bs     = (float*)(ws + 34772992);       // 7*128 fp32 scaled biases
    float*  dinv   = (float*)(ws + 34776576);       // NN floats
    int*    cnt    = (int*)  (ws + 34896576);       // NN ints
    int*    row_ptr= (int*)  (ws + 35016576);       // NN+1 ints (padded)
    int*    cursor = (int*)  (ws + 35136640);       // NN ints
    int2*   csr    = (int2*) (ws + 35256640);       // NE int2

    int* bsum = (int*)bufA;   // NB ints (bufA unused until final stage)

    hipMemsetAsync(cnt, 0, NN * sizeof(int), stream);
    k_count<<<(NE + 255) / 256, 256, 0, stream>>>(ei, cnt, W0, Wh, b0, bh, x,
                                                  W0t16, Wht16, bs, x16);
    k_scan1<<<NB, 256, 0, stream>>>(cnt, bsum, dinv);
    k_scan3<<<NB, 256, 0, stream>>>(cnt, bsum, row_ptr, cursor);
    k_fill<<<(NE + 255) / 256, 256, 0, stream>>>(ei, dinv, cursor, csr);

    // layer 0 (fused agg+MFMA, fp16 x): h1' = fp16(lrelu((A_hat x) @ (S*W0) + S*b0))
    k_layer0<<<NN / 16, 256, 0, stream>>>(x16, row_ptr, csr, dinv, W0t16, bs, bufB16);

    // hidden layers 1..5 (fused agg+MFMA), ping-pong; layer 6 additionally fuses
    // the out-GEMM (u = h7' @ Wout) and skips the h7' global store.
    __half* hin = bufB16;
    __half* hout = bufC16;
    for (int i = 0; i < 5; i++) {
        k_layer_h<false><<<NN / 16, 256, 0, stream>>>(hin, row_ptr, csr, dinv,
                                                      Wht16 + (size_t)i * 16384,
                                                      bs + 128 + (size_t)i * 128, hout,
                                                      Wout, bufA);
        __half* t = hin; hin = hout; hout = t;
    }
    k_layer_h<true><<<NN / 16, 256, 0, stream>>>(hin, row_ptr, csr, dinv,
                                                 Wht16 + (size_t)5 * 16384,
                                                 bs + 128 + (size_t)5 * 128, hout,
                                                 Wout, bufA /* u' : NN x 3 */);

    // final: out = tanh((A_hat u') / S + bout) * 0.5
    k_agg_out<<<(NN + 255) / 256, 256, 0, stream>>>(bufA, row_ptr, csr, dinv, bout, out);
}

// Round 14
// 316.481 us; speedup vs baseline: 1.0381x; 1.0381x over previous
//
#include <hip/hip_runtime.h>
#include <hip/hip_fp16.h>
#include <math.h>

#define NN 30000
#define NE 480000
#define NB 118   // ceil(NN/256)
#define SCALE 512.0f
#define INVSCALE (1.0f / 512.0f)

typedef _Float16 half8 __attribute__((ext_vector_type(8)));
typedef float floatx4 __attribute__((ext_vector_type(4)));

__device__ __forceinline__ float lrelu(float v) { return v > 0.0f ? v : v * 0.02f; }

__device__ __forceinline__ float4 fma4(float4 v, float w, float4 a) {
    a.x = fmaf(v.x, w, a.x);
    a.y = fmaf(v.y, w, a.y);
    a.z = fmaf(v.z, w, a.z);
    a.w = fmaf(v.w, w, a.w);
    return a;
}

__device__ __forceinline__ float4 loadh4(const __half* p) {
    uint2 raw = *(const uint2*)p;
    float2 f0 = __half22float2(*(__half2*)&raw.x);
    float2 f1 = __half22float2(*(__half2*)&raw.y);
    return make_float4(f0.x, f0.y, f1.x, f1.y);
}

__device__ __forceinline__ void loadh8(const __half* p, float4* lo, float4* hi) {
    uint4 raw = *(const uint4*)p;
    float2 f0 = __half22float2(*(__half2*)&raw.x);
    float2 f1 = __half22float2(*(__half2*)&raw.y);
    float2 f2 = __half22float2(*(__half2*)&raw.z);
    float2 f3 = __half22float2(*(__half2*)&raw.w);
    *lo = make_float4(f0.x, f0.y, f1.x, f1.y);
    *hi = make_float4(f2.x, f2.y, f3.x, f3.y);
}

// non-temporal half store: h-output is a write-once stream consumed a whole kernel
// later (7.7MB buffer, can't be L2-resident anyway) -> keep it out of L2 so the
// gather working set keeps the cache.
// // NT csr LOADS (R13) regressed +11us: 16 lanes/node broadcast-read the same csr
// // entry; NT bypassed L1/L2 broadcast -> up to 16x refetch. csr loads stay cached.
__device__ __forceinline__ void stnt_h(__half* p, float v) {
    __half hh = __float2half(v);
    __builtin_nontemporal_store(*(_Float16*)&hh, (_Float16*)p);
}

// ---------------- CSR build (+ fused weight convert + x->fp16) ----------------

__global__ void k_count(const int* __restrict__ ei, int* __restrict__ cnt,
                        const float* __restrict__ W0, const float* __restrict__ Wh,
                        const float* __restrict__ b0, const float* __restrict__ bh,
                        const float* __restrict__ x,
                        __half* __restrict__ W0t, __half* __restrict__ Wht,
                        float* __restrict__ bs, __half* __restrict__ x16) {
    int g = blockIdx.x * 256 + threadIdx.x;
    if (g < NE) atomicAdd(&cnt[ei[NE + g]], 1);
    {   // x -> fp16: 1.92M elements, 4 per thread
        float4 v = *(const float4*)&x[(size_t)g * 4];
        __half2 a = __floats2half2_rn(v.x, v.y);
        __half2 b = __floats2half2_rn(v.z, v.w);
        uint2 pk;
        pk.x = *(unsigned int*)&a;
        pk.y = *(unsigned int*)&b;
        *(uint2*)&x16[(size_t)g * 4] = pk;
    }
    if (g < 8192) {                       // W0 [64,128] -> W0t [128n][64k], *SCALE
        int k = g >> 7, n = g & 127;
        W0t[n * 64 + k] = __float2half(W0[g] * SCALE);
    } else if (g < 8192 + 98304) {        // Wh [6][128,128] -> Wht [6][128n][128k]
        int j = g - 8192;
        int l = j >> 14;
        int r = j & 16383;
        int k = r >> 7, n = r & 127;
        Wht[l * 16384 + n * 128 + k] = __float2half(Wh[j]);
    } else if (g < 8192 + 98304 + 896) {  // biases: [b0 | bh0..bh5] * SCALE
        int j = g - 8192 - 98304;
        bs[j] = (j < 128 ? b0[j] : bh[j - 128]) * SCALE;
    }
}

__global__ void k_scan1(const int* __restrict__ cnt, int* __restrict__ bsum,
                        float* __restrict__ dinv) {
    __shared__ int sd[256];
    int tid = threadIdx.x;
    int i = blockIdx.x * 256 + tid;
    int v = (i < NN) ? cnt[i] : 0;
    if (i < NN) dinv[i] = 1.0f / sqrtf((float)(v + 1));  // +1 self loop
    sd[tid] = v;
    __syncthreads();
    for (int off = 128; off > 0; off >>= 1) {
        if (tid < off) sd[tid] += sd[tid + off];
        __syncthreads();
    }
    if (tid == 0) bsum[blockIdx.x] = sd[0];
}

__global__ void k_scan3(const int* __restrict__ cnt, const int* __restrict__ bsum,
                        int* __restrict__ row_ptr, int* __restrict__ cursor) {
    __shared__ int sd[256];
    __shared__ int offs[128];
    int tid = threadIdx.x;
    if (tid < 128) offs[tid] = (tid < blockIdx.x) ? bsum[tid] : 0;
    __syncthreads();
    for (int o = 64; o > 0; o >>= 1) {
        if (tid < o) offs[tid] += offs[tid + o];
        __syncthreads();
    }
    int i = blockIdx.x * 256 + tid;
    int v = (i < NN) ? cnt[i] : 0;
    sd[tid] = v;
    __syncthreads();
    for (int off = 1; off < 256; off <<= 1) {
        int t = (tid >= off) ? sd[tid - off] : 0;
        __syncthreads();
        sd[tid] += t;
        __syncthreads();
    }
    if (i < NN) {
        int excl = offs[0] + sd[tid] - v;
        row_ptr[i] = excl;
        cursor[i] = excl;
        if (i == NN - 1) row_ptr[NN] = excl + v;
    }
}

__global__ void k_fill(const int* __restrict__ ei, const float* __restrict__ dinv,
                       int* __restrict__ cursor, int2* __restrict__ csr) {
    int e = blockIdx.x * 256 + threadIdx.x;
    if (e < NE) {
        int s = ei[e];
        int d = ei[NE + e];
        int pos = atomicAdd(&cursor[d], 1);
        float w = dinv[s] * dinv[d];
        csr[pos] = make_int2(s, __float_as_int(w));
    }
}

// ================= fused layer kernels: agg -> LDS (A-fragment order) -> MFMA =================
// Block = 16 nodes (one 16-row MFMA tile), 256 threads (4 waves), 16 thr/node agg phase.
// LDS hsF[ks][quad][row16][8]: MFMA-side ds_read_b128 2-way aliased (free).
// NN % 16 == 0: no tail guards.
// // mega-kernel attempt (R11) failed: cooperative launch never ran (all-zero out).

// ---- layer 0: x16 fp16 [NN,64] -> out16 = fp16(lrelu((A_hat x) @ W0t + bias)) ----
__launch_bounds__(256)
__global__ void k_layer0(const __half* __restrict__ x, const int* __restrict__ row_ptr,
                         const int2* __restrict__ csr, const float* __restrict__ dinv,
                         const __half* __restrict__ Wt, const float* __restrict__ bias,
                         __half* __restrict__ out16) {
    __shared__ _Float16 hsF[2 * 4 * 16 * 8];  // 2 KB
    int tid = threadIdx.x;
    int node0 = blockIdx.x * 16;
    {
        int nl = tid >> 4;
        int node = node0 + nl;
        int c = (tid & 15) * 4;          // 4 fp16 ch / lane (8B loads)
        float di = dinv[node];
        float w0 = di * di;
        float4 hv = loadh4(&x[(size_t)node * 64 + c]);
        float4 acc[8];
        acc[0] = make_float4(hv.x * w0, hv.y * w0, hv.z * w0, hv.w * w0);
        #pragma unroll
        for (int j = 1; j < 8; j++) acc[j] = make_float4(0.f, 0.f, 0.f, 0.f);
        int e = row_ptr[node];
        int e1 = row_ptr[node + 1];
        for (; e + 8 <= e1; e += 8) {
            int2 sw[8];
            #pragma unroll
            for (int j = 0; j < 8; j++) sw[j] = csr[e + j];
            float4 v[8];
            #pragma unroll
            for (int j = 0; j < 8; j++) v[j] = loadh4(&x[(size_t)sw[j].x * 64 + c]);
            #pragma unroll
            for (int j = 0; j < 8; j++) acc[j] = fma4(v[j], __int_as_float(sw[j].y), acc[j]);
        }
        for (; e < e1; ++e) {
            int2 sw = csr[e];
            float4 v = loadh4(&x[(size_t)sw.x * 64 + c]);
            acc[0] = fma4(v, __int_as_float(sw.y), acc[0]);
        }
        #pragma unroll
        for (int j = 1; j < 8; j++) {
            acc[0].x += acc[j].x;
            acc[0].y += acc[j].y;
            acc[0].z += acc[j].z;
            acc[0].w += acc[j].w;
        }
        int ks = c >> 5, quad = (c >> 3) & 3, jj = c & 7;
        __half2 p0 = __floats2half2_rn(acc[0].x, acc[0].y);
        __half2 p1 = __floats2half2_rn(acc[0].z, acc[0].w);
        uint2 pk;
        pk.x = *(unsigned int*)&p0;
        pk.y = *(unsigned int*)&p1;
        *(uint2*)&hsF[((ks * 4 + quad) * 16 + nl) * 8 + jj] = pk;
    }
    __syncthreads();
    int wave = tid >> 6, lane = tid & 63, quad = lane >> 4, ln = lane & 15;
    half8 afrag[2];
    #pragma unroll
    for (int ks = 0; ks < 2; ks++)
        afrag[ks] = *(const half8*)&hsF[((ks * 4 + quad) * 16 + ln) * 8];
    #pragma unroll
    for (int tc = 0; tc < 2; tc++) {
        int tt = wave + tc * 4;
        floatx4 acc = (floatx4){0.f, 0.f, 0.f, 0.f};
        #pragma unroll
        for (int ks = 0; ks < 2; ks++) {
            half8 b = *(const half8*)&Wt[(size_t)(tt * 16 + ln) * 64 + ks * 32 + quad * 8];
            acc = __builtin_amdgcn_mfma_f32_16x16x32_f16(afrag[ks], b, acc, 0, 0, 0);
        }
        int col = tt * 16 + ln;
        float bb = bias[col];
        #pragma unroll
        for (int r = 0; r < 4; r++) {
            int row = node0 + quad * 4 + r;
            stnt_h(&out16[(size_t)row * 128 + col], lrelu(acc[r] + bb));
        }
    }
}

// ---- hidden layer: h fp16 [NN,128] -> out16 = fp16(lrelu((A_hat h) @ Wt + bias)) ----
// LAST=true: u = h7' @ Wout computed in-block; h7' never hits global.
template <bool LAST>
__launch_bounds__(256)
__global__ void k_layer_h(const __half* __restrict__ h, const int* __restrict__ row_ptr,
                          const int2* __restrict__ csr, const float* __restrict__ dinv,
                          const __half* __restrict__ Wt, const float* __restrict__ bias,
                          __half* __restrict__ out16, const float* __restrict__ Wout,
                          float* __restrict__ u) {
    __shared__ _Float16 hsF[4 * 4 * 16 * 8];  // 4 KB
    __shared__ float uacc[4][16][3];          // cross-wave u partials (LAST only)
    int tid = threadIdx.x;
    int node0 = blockIdx.x * 16;
    {
        int nl = tid >> 4;
        int node = node0 + nl;
        int c = (tid & 15) * 8;      // 8 fp16 ch / lane (16B b128 loads)
        float di = dinv[node];
        float w0 = di * di;
        float4 hlo, hhi;
        loadh8(&h[(size_t)node * 128 + c], &hlo, &hhi);
        float4 acc[4][2];
        acc[0][0] = make_float4(hlo.x * w0, hlo.y * w0, hlo.z * w0, hlo.w * w0);
        acc[0][1] = make_float4(hhi.x * w0, hhi.y * w0, hhi.z * w0, hhi.w * w0);
        #pragma unroll
        for (int j = 1; j < 4; j++) {
            acc[j][0] = make_float4(0.f, 0.f, 0.f, 0.f);
            acc[j][1] = make_float4(0.f, 0.f, 0.f, 0.f);
        }
        int e = row_ptr[node];
        int e1 = row_ptr[node + 1];
        for (; e + 4 <= e1; e += 4) {
            int2 sw[4];
            #pragma unroll
            for (int j = 0; j < 4; j++) sw[j] = csr[e + j];
            float4 vlo[4], vhi[4];
            #pragma unroll
            for (int j = 0; j < 4; j++)
                loadh8(&h[(size_t)sw[j].x * 128 + c], &vlo[j], &vhi[j]);
            #pragma unroll
            for (int j = 0; j < 4; j++) {
                float w = __int_as_float(sw[j].y);
                acc[j][0] = fma4(vlo[j], w, acc[j][0]);
                acc[j][1] = fma4(vhi[j], w, acc[j][1]);
            }
        }
        for (; e < e1; ++e) {
            int2 sw = csr[e];
            float4 vlo, vhi;
            loadh8(&h[(size_t)sw.x * 128 + c], &vlo, &vhi);
            float w = __int_as_float(sw.y);
            acc[0][0] = fma4(vlo, w, acc[0][0]);
            acc[0][1] = fma4(vhi, w, acc[0][1]);
        }
        #pragma unroll
        for (int j = 1; j < 4; j++) {
            acc[0][0].x += acc[j][0].x; acc[0][0].y += acc[j][0].y;
            acc[0][0].z += acc[j][0].z; acc[0][0].w += acc[j][0].w;
            acc[0][1].x += acc[j][1].x; acc[0][1].y += acc[j][1].y;
            acc[0][1].z += acc[j][1].z; acc[0][1].w += acc[j][1].w;
        }
        int ks = c >> 5, quad = (c >> 3) & 3;
        __half2 p0 = __floats2half2_rn(acc[0][0].x, acc[0][0].y);
        __half2 p1 = __floats2half2_rn(acc[0][0].z, acc[0][0].w);
        __half2 p2 = __floats2half2_rn(acc[0][1].x, acc[0][1].y);
        __half2 p3 = __floats2half2_rn(acc[0][1].z, acc[0][1].w);
        uint4 pk;
        pk.x = *(unsigned int*)&p0;
        pk.y = *(unsigned int*)&p1;
        pk.z = *(unsigned int*)&p2;
        pk.w = *(unsigned int*)&p3;
        *(uint4*)&hsF[((ks * 4 + quad) * 16 + nl) * 8] = pk;
    }
    __syncthreads();
    int wave = tid >> 6, lane = tid & 63, quad = lane >> 4, ln = lane & 15;
    half8 afrag[4];
    #pragma unroll
    for (int ks = 0; ks < 4; ks++)
        afrag[ks] = *(const half8*)&hsF[((ks * 4 + quad) * 16 + ln) * 8];

    float up[4][3];
    if (LAST) {
        #pragma unroll
        for (int r = 0; r < 4; r++)
            #pragma unroll
            for (int cc = 0; cc < 3; cc++) up[r][cc] = 0.f;
    }

    #pragma unroll
    for (int tc = 0; tc < 2; tc++) {
        int tt = wave + tc * 4;
        floatx4 acc = (floatx4){0.f, 0.f, 0.f, 0.f};
        #pragma unroll
        for (int ks = 0; ks < 4; ks++) {
            half8 b = *(const half8*)&Wt[(size_t)(tt * 16 + ln) * 128 + ks * 32 + quad * 8];
            acc = __builtin_amdgcn_mfma_f32_16x16x32_f16(afrag[ks], b, acc, 0, 0, 0);
        }
        int col = tt * 16 + ln;
        float bb = bias[col];
        if (LAST) {
            float w0o = Wout[col * 3 + 0];
            float w1o = Wout[col * 3 + 1];
            float w2o = Wout[col * 3 + 2];
            #pragma unroll
            for (int r = 0; r < 4; r++) {
                float hv = __half2float(__float2half(lrelu(acc[r] + bb)));
                up[r][0] = fmaf(hv, w0o, up[r][0]);
                up[r][1] = fmaf(hv, w1o, up[r][1]);
                up[r][2] = fmaf(hv, w2o, up[r][2]);
            }
        } else {
            #pragma unroll
            for (int r = 0; r < 4; r++) {
                int row = node0 + quad * 4 + r;
                stnt_h(&out16[(size_t)row * 128 + col], lrelu(acc[r] + bb));
            }
        }
    }

    if (LAST) {
        #pragma unroll
        for (int m = 1; m < 16; m <<= 1) {
            #pragma unroll
            for (int r = 0; r < 4; r++) {
                #pragma unroll
                for (int cc = 0; cc < 3; cc++)
                    up[r][cc] += __shfl_xor(up[r][cc], m);
            }
        }
        if (ln == 0) {
            #pragma unroll
            for (int r = 0; r < 4; r++) {
                #pragma unroll
                for (int cc = 0; cc < 3; cc++)
                    uacc[wave][quad * 4 + r][cc] = up[r][cc];
            }
        }
        __syncthreads();
        if (tid < 48) {
            int row = tid / 3, cc = tid % 3;
            float s = (uacc[0][row][cc] + uacc[1][row][cc]) +
                      (uacc[2][row][cc] + uacc[3][row][cc]);
            u[(size_t)(node0 + row) * 3 + cc] = s;
        }
    }
}

// ---------------- final aggregate (3 ch), unscale, + bias, tanh*0.5 ----------------

__global__ void k_agg_out(const float* __restrict__ u, const int* __restrict__ row_ptr,
                          const int2* __restrict__ csr, const float* __restrict__ dinv,
                          const float* __restrict__ bout, float* __restrict__ out) {
    int node = blockIdx.x * 256 + threadIdx.x;
    if (node >= NN) return;
    float di = dinv[node], w0 = di * di;
    float s0 = u[(size_t)node * 3 + 0] * w0;
    float s1 = u[(size_t)node * 3 + 1] * w0;
    float s2 = u[(size_t)node * 3 + 2] * w0;
    float b0a = 0.f, b1a = 0.f, b2a = 0.f;
    int e = row_ptr[node];
    int e1 = row_ptr[node + 1];
    for (; e + 2 <= e1; e += 2) {
        int2 swa = csr[e], swb = csr[e + 1];
        float wa = __int_as_float(swa.y), wb = __int_as_float(swb.y);
        const float* ua = &u[(size_t)swa.x * 3];
        const float* ub = &u[(size_t)swb.x * 3];
        s0 = fmaf(ua[0], wa, s0);
        s1 = fmaf(ua[1], wa, s1);
        s2 = fmaf(ua[2], wa, s2);
        b0a = fmaf(ub[0], wb, b0a);
        b1a = fmaf(ub[1], wb, b1a);
        b2a = fmaf(ub[2], wb, b2a);
    }
    for (; e < e1; ++e) {
        int2 sw = csr[e];
        float w = __int_as_float(sw.y);
        const float* us = &u[(size_t)sw.x * 3];
        s0 = fmaf(us[0], w, s0);
        s1 = fmaf(us[1], w, s1);
        s2 = fmaf(us[2], w, s2);
    }
    out[(size_t)node * 3 + 0] = tanhf((s0 + b0a) * INVSCALE + bout[0]) * 0.5f;
    out[(size_t)node * 3 + 1] = tanhf((s1 + b1a) * INVSCALE + bout[1]) * 0.5f;
    out[(size_t)node * 3 + 2] = tanhf((s2 + b2a) * INVSCALE + bout[2]) * 0.5f;
}

// ---------------- launch ----------------

extern "C" void kernel_launch(void* const* d_in, const int* in_sizes, int n_in,
                              void* d_out, int out_size, void* d_ws, size_t ws_size,
                              hipStream_t stream) {
    const float* x        = (const float*)d_in[0];
    const int*   ei       = (const int*)d_in[1];   // int32: [2, NE] row-major
    const float* W0       = (const float*)d_in[2];
    const float* b0       = (const float*)d_in[3];
    const float* Wh       = (const float*)d_in[4];
    const float* bh       = (const float*)d_in[5];
    const float* Wout     = (const float*)d_in[6];
    const float* bout     = (const float*)d_in[7];
    float* out            = (float*)d_out;

    char* ws = (char*)d_ws;
    float*  bufA   = (float*)(ws + 0);              // u (NN x 3 fp32) + scan temps
    __half* bufB16 = (__half*)(ws + 15360000);      // NN*128 fp16
    __half* bufC16 = (__half*)(ws + 23040000);      // NN*128 fp16
    __half* x16    = (__half*)(ws + 30720000);      // NN*64 fp16
    __half* W0t16  = (__half*)(ws + 34560000);      // 128*64 fp16
    __half* Wht16  = (__half*)(ws + 34576384);      // 6*128*128 fp16
    float*  bs     = (float*)(ws + 34772992);       // 7*128 fp32 scaled biases
    float*  dinv   = (float*)(ws + 34776576);       // NN floats
    int*    cnt    = (int*)  (ws + 34896576);       // NN ints
    int*    row_ptr= (int*)  (ws + 35016576);       // NN+1 ints (padded)
    int*    cursor = (int*)  (ws + 35136640);       // NN ints
    int2*   csr    = (int2*) (ws + 35256640);       // NE int2

    int* bsum = (int*)bufA;   // NB ints (bufA unused until final stage)

    hipMemsetAsync(cnt, 0, NN * sizeof(int), stream);
    k_count<<<(NE + 255) / 256, 256, 0, stream>>>(ei, cnt, W0, Wh, b0, bh, x,
                                                  W0t16, Wht16, bs, x16);
    k_scan1<<<NB, 256, 0, stream>>>(cnt, bsum, dinv);
    k_scan3<<<NB, 256, 0, stream>>>(cnt, bsum, row_ptr, cursor);
    k_fill<<<(NE + 255) / 256, 256, 0, stream>>>(ei, dinv, cursor, csr);

    // layer 0 (fused agg+MFMA, fp16 x): h1' = fp16(lrelu((A_hat x) @ (S*W0) + S*b0))
    k_layer0<<<NN / 16, 256, 0, stream>>>(x16, row_ptr, csr, dinv, W0t16, bs, bufB16);

    // hidden layers 1..5 (fused agg+MFMA), ping-pong; layer 6 additionally fuses
    // the out-GEMM (u = h7' @ Wout) and skips the h7' global store.
    __half* hin = bufB16;
    __half* hout = bufC16;
    for (int i = 0; i < 5; i++) {
        k_layer_h<false><<<NN / 16, 256, 0, stream>>>(hin, row_ptr, csr, dinv,
                                                      Wht16 + (size_t)i * 16384,
                                                      bs + 128 + (size_t)i * 128, hout,
                                                      Wout, bufA);
        __half* t = hin; hin = hout; hout = t;
    }
    k_layer_h<true><<<NN / 16, 256, 0, stream>>>(hin, row_ptr, csr, dinv,
                                                 Wht16 + (size_t)5 * 16384,
                                                 bs + 128 + (size_t)5 * 128, hout,
                                                 Wout, bufA /* u' : NN x 3 */);

    // final: out = tanh((A_hat u') / S + bout) * 0.5
    k_agg_out<<<(NN + 255) / 256, 256, 0, stream>>>(bufA, row_ptr, csr, dinv, bout, out);
}